// Round 1
// baseline (698.497 us; speedup 1.0000x reference)
//
#include <hip/hip_runtime.h>
#include <stdint.h>

#define NND 100000
#define HD  128
#define BB  512
#define DD  32
#define NNEG 5
#define CAP 12

// ---------------- workspace layout (bytes) ----------------
// [0)        ticket        (int, padded)
// [256)      done[512]     (int)
// [4096)     wcnt[NND]     (int)
// [404096)   wsteps[NND*CAP] (int, packed s*64+slot)
// [5204096)  dep[BB*38]    (int, packed last-writer or -1)
// [5281920)  step_out[BB*33*HD] (float)
// total ~13.94 MB
#define OFF_TICKET   0
#define OFF_DONE     256
#define OFF_WCNT     4096
#define OFF_WSTEPS   404096
#define OFF_DEP      5204096
#define OFF_STEPOUT  5281920
#define ZERO_BYTES   404096   // ticket+done+wcnt

__global__ void build_writers(const int* __restrict__ u,
                              const int* __restrict__ nb,
                              int* __restrict__ wcnt,
                              int* __restrict__ wsteps) {
    int id = blockIdx.x * blockDim.x + threadIdx.x;
    if (id >= BB * 33) return;
    int s = id / 33, slot = id % 33;
    int row = (slot == 0) ? u[s] : nb[s * DD + slot - 1];
    int pos = atomicAdd(&wcnt[row], 1);
    if (pos < CAP) wsteps[row * CAP + pos] = s * 64 + slot;
}

__global__ void build_deps(const int* __restrict__ u,
                           const int* __restrict__ nb,
                           const int* __restrict__ neg,
                           const int* __restrict__ wcnt,
                           const int* __restrict__ wsteps,
                           int* __restrict__ dep) {
    int id = blockIdx.x * blockDim.x + threadIdx.x;
    if (id >= BB * 38) return;
    int t = id / 38, i = id % 38;
    int row = (i == 0) ? u[t] : (i < 33) ? nb[t * DD + i - 1]
                                         : neg[t * NNEG + i - 33];
    int lim = t * 64;
    int best = -1;
    int n = wcnt[row]; if (n > CAP) n = CAP;
    for (int p = 0; p < n; p++) {
        int e = wsteps[row * CAP + p];
        if (e < lim && e > best) best = e;   // max (step,slot) < t  == numpy last-write-wins
    }
    dep[id] = best;
}

__global__ __launch_bounds__(256, 2)
void dyrep_main(const float* __restrict__ time_bar,
                const float* __restrict__ time_cur,
                const float* __restrict__ time_delta,
                const int* __restrict__ u,
                const int* __restrict__ nb,
                const int* __restrict__ neg,
                const float* __restrict__ z0,
                const float* __restrict__ W_omega, const float* __restrict__ b_omega,
                const float* __restrict__ W_h,     const float* __restrict__ b_h,
                const float* __restrict__ W_e2n,   const float* __restrict__ b_e2n,
                const float* __restrict__ W_rec_e, const float* __restrict__ b_rec_e,
                const float* __restrict__ W_rec_n, const float* __restrict__ b_rec_n,
                const float* __restrict__ W_time,  const float* __restrict__ b_time,
                const float* __restrict__ w_t_p,   const float* __restrict__ alpha_p,
                const float* __restrict__ psi_p,
                int* ticket, int* done,
                const int* __restrict__ dep,
                float* __restrict__ step_out,
                float* __restrict__ out) {
    __shared__ int t_sh;
    __shared__ __align__(16) float zbuf[38][HD];   // 0=u, 1..32=nb, 33..37=neg
    __shared__ float sv[3][HD];                    // z_u@W_e2n, z_u@W_rec_e, m@W_h
    __shared__ float mvec[HD];
    __shared__ float td_arr[33];
    __shared__ const float* srcp[38];
    __shared__ int src_is_so[38];

    const int tid = threadIdx.x;
    if (tid == 0) t_sh = atomicAdd(ticket, 1);
    __syncthreads();
    const int t = t_sh;

    // ---- resolve sources + spin on dependencies (wave 0) ----
    if (tid < 64) {
        int i = tid;
        int d = (i < 38) ? dep[t * 38 + i] : -1;
        if (i < 38) {
            if (d >= 0) {
                srcp[i] = step_out + (size_t)(d >> 6) * 33 * HD + (size_t)(d & 63) * HD;
                src_is_so[i] = 1;
            } else {
                int row = (i == 0) ? u[t] : (i < 33) ? nb[t * DD + i - 1]
                                                     : neg[t * NNEG + i - 33];
                srcp[i] = z0 + (size_t)row * HD;
                src_is_so[i] = 0;
            }
        }
        bool waiting = (d >= 0);
        int s = waiting ? (d >> 6) : 0;
        while (true) {
            bool nw = waiting &&
                (__hip_atomic_load(&done[s], __ATOMIC_RELAXED, __HIP_MEMORY_SCOPE_AGENT) == 0);
            if (__ballot(nw) == 0ULL) break;
            waiting = nw;
            __builtin_amdgcn_s_sleep(2);
        }
    }
    __syncthreads();
    __threadfence();   // acquire: invalidate stale L1/L2 before reading step_out

    // ---- stage 38 rows into LDS ----
    for (int idx = tid; idx < 38 * (HD / 4); idx += 256) {
        int slot = idx >> 5;
        int c4 = idx & 31;
        const float* sp = srcp[slot] + c4 * 4;
        float4 v;
        if (src_is_so[slot]) {
            const uint32_t* ip = (const uint32_t*)sp;
            uint32_t x0 = __hip_atomic_load(ip + 0, __ATOMIC_RELAXED, __HIP_MEMORY_SCOPE_AGENT);
            uint32_t x1 = __hip_atomic_load(ip + 1, __ATOMIC_RELAXED, __HIP_MEMORY_SCOPE_AGENT);
            uint32_t x2 = __hip_atomic_load(ip + 2, __ATOMIC_RELAXED, __HIP_MEMORY_SCOPE_AGENT);
            uint32_t x3 = __hip_atomic_load(ip + 3, __ATOMIC_RELAXED, __HIP_MEMORY_SCOPE_AGENT);
            v = make_float4(__uint_as_float(x0), __uint_as_float(x1),
                            __uint_as_float(x2), __uint_as_float(x3));
        } else {
            v = *(const float4*)sp;
        }
        *(float4*)&zbuf[slot][c4 * 4] = v;
    }
    const float tc = time_cur[t];
    __syncthreads();

    // ---- mean of neighbor rows + positional td ----
    if (tid < HD) {
        float s = 0.f;
        #pragma unroll
        for (int j = 1; j <= 32; j++) s += zbuf[j][tid];
        mvec[tid] = s * (1.0f / 32.0f);
    } else if (tid < HD + 33) {
        int j = tid - HD;
        td_arr[j] = tc - time_bar[(size_t)t * NND + j];
    }
    __syncthreads();

    // ---- single-row matvecs ----
    if (tid < HD) {
        float a1 = 0.f, a2 = 0.f;
        for (int k = 0; k < HD; k++) {
            float a = zbuf[0][k];
            a1 = fmaf(a, W_e2n[k * HD + tid], a1);
            a2 = fmaf(a, W_rec_e[k * HD + tid], a2);
        }
        sv[0][tid] = a1; sv[1][tid] = a2;
    } else {
        int o = tid - HD;
        float a3 = 0.f;
        for (int k = 0; k < HD; k++) a3 = fmaf(mvec[k], W_h[k * HD + o], a3);
        sv[2][o] = a3;
    }

    // ---- 32x128 @ 128x128 GEMM, 4x4 register tiles ----
    const int cg = tid & 31, rg = tid >> 5;
    const int c0 = cg * 4, r0 = rg * 4;
    float acc[4][4];
    #pragma unroll
    for (int r = 0; r < 4; r++)
        #pragma unroll
        for (int c = 0; c < 4; c++) acc[r][c] = 0.f;

    for (int kb = 0; kb < HD; kb += 4) {
        float av[4][4], wv[4][4];
        #pragma unroll
        for (int r = 0; r < 4; r++) {
            float4 aa = *(const float4*)&zbuf[1 + r0 + r][kb];
            av[r][0] = aa.x; av[r][1] = aa.y; av[r][2] = aa.z; av[r][3] = aa.w;
        }
        #pragma unroll
        for (int kk = 0; kk < 4; kk++) {
            float4 ww = *(const float4*)&W_rec_n[(size_t)(kb + kk) * HD + c0];
            wv[kk][0] = ww.x; wv[kk][1] = ww.y; wv[kk][2] = ww.z; wv[kk][3] = ww.w;
        }
        #pragma unroll
        for (int r = 0; r < 4; r++)
            #pragma unroll
            for (int c = 0; c < 4; c++) {
                float s = acc[r][c];
                s = fmaf(av[r][0], wv[0][c], s);
                s = fmaf(av[r][1], wv[1][c], s);
                s = fmaf(av[r][2], wv[2][c], s);
                s = fmaf(av[r][3], wv[3][c], s);
                acc[r][c] = s;
            }
    }
    __syncthreads();

    // ---- epilogue: h_nb ----
    float* my_out = step_out + (size_t)t * 33 * HD;
    #pragma unroll
    for (int r = 0; r < 4; r++) {
        int jj = r0 + r;
        float tdj = td_arr[1 + jj];
        #pragma unroll
        for (int c = 0; c < 4; c++) {
            int oo = c0 + c;
            float pre = acc[r][c] + sv[0][oo] + b_e2n[oo] + b_rec_n[oo]
                        + tdj * W_time[oo] + b_time[oo];
            my_out[(size_t)(1 + jj) * HD + oo] = 1.f / (1.f + __expf(-pre));
        }
    }
    // ---- h_u ----
    if (tid < HD) {
        float pre = sv[2][tid] + b_h[tid] + sv[1][tid] + b_rec_e[tid]
                    + td_arr[0] * W_time[tid] + b_time[tid];
        my_out[tid] = 1.f / (1.f + __expf(-pre));
    }

    // ---- Hawkes intensities on pre-update embeddings (wave 0) ----
    if (tid < 64) {
        int lane = tid;
        float wt = *w_t_p, al = *alpha_p, ps = *psi_p, bom = *b_omega;
        float wo0 = W_omega[lane], wo1 = W_omega[lane + 64];
        for (int d = 0; d < 6; d++) {
            int slot = (d == 0) ? 0 : 32 + d;   // 0 or 33..37
            float v = zbuf[slot][lane] * wo0 + zbuf[slot][lane + 64] * wo1;
            #pragma unroll
            for (int off = 32; off; off >>= 1) v += __shfl_down(v, off);
            if (lane == 0) {
                float tdv;
                if (d == 0) tdv = tc - time_delta[t * 2 + 0];
                else {
                    int nn = neg[t * NNEG + (d - 1)];
                    tdv = tc - time_bar[(size_t)t * NND + nn];
                }
                float g = v + bom + al * __expf(-wt * tdv);
                float x = g / ps;
                float spv = fmaxf(x, 0.f) + log1pf(__expf(-fabsf(x)));
                float lam = ps * spv;
                if (d == 0) out[t] = lam;
                else out[BB + t * NNEG + (d - 1)] = lam * (1.0f / NNEG);
            }
        }
    }

    // ---- publish ----
    __syncthreads();
    if (tid == 0) {
        __threadfence();   // release: flush to coherence point (cross-XCD)
        __hip_atomic_store(&done[t], 1, __ATOMIC_RELEASE, __HIP_MEMORY_SCOPE_AGENT);
    }
}

extern "C" void kernel_launch(void* const* d_in, const int* in_sizes, int n_in,
                              void* d_out, int out_size, void* d_ws, size_t ws_size,
                              hipStream_t stream) {
    const float* time_bar  = (const float*)d_in[0];
    const float* time_cur  = (const float*)d_in[1];
    const float* time_delta= (const float*)d_in[2];
    const int*   u         = (const int*)d_in[3];
    const int*   nb        = (const int*)d_in[4];
    const int*   neg       = (const int*)d_in[5];
    const float* z0        = (const float*)d_in[6];
    const float* W_omega   = (const float*)d_in[7];
    const float* b_omega   = (const float*)d_in[8];
    const float* W_h       = (const float*)d_in[9];
    const float* b_h       = (const float*)d_in[10];
    const float* W_e2n     = (const float*)d_in[11];
    const float* b_e2n     = (const float*)d_in[12];
    const float* W_rec_e   = (const float*)d_in[13];
    const float* b_rec_e   = (const float*)d_in[14];
    const float* W_rec_n   = (const float*)d_in[15];
    const float* b_rec_n   = (const float*)d_in[16];
    const float* W_time    = (const float*)d_in[17];
    const float* b_time    = (const float*)d_in[18];
    const float* w_t       = (const float*)d_in[19];
    const float* alpha     = (const float*)d_in[20];
    const float* psi       = (const float*)d_in[21];

    char* ws = (char*)d_ws;
    int*   ticket   = (int*)(ws + OFF_TICKET);
    int*   done     = (int*)(ws + OFF_DONE);
    int*   wcnt     = (int*)(ws + OFF_WCNT);
    int*   wsteps   = (int*)(ws + OFF_WSTEPS);
    int*   dep      = (int*)(ws + OFF_DEP);
    float* step_out = (float*)(ws + OFF_STEPOUT);
    float* out      = (float*)d_out;

    hipMemsetAsync(ws, 0, ZERO_BYTES, stream);
    build_writers<<<(BB * 33 + 255) / 256, 256, 0, stream>>>(u, nb, wcnt, wsteps);
    build_deps<<<(BB * 38 + 255) / 256, 256, 0, stream>>>(u, nb, neg, wcnt, wsteps, dep);
    dyrep_main<<<BB, 256, 0, stream>>>(time_bar, time_cur, time_delta, u, nb, neg, z0,
                                       W_omega, b_omega, W_h, b_h, W_e2n, b_e2n,
                                       W_rec_e, b_rec_e, W_rec_n, b_rec_n,
                                       W_time, b_time, w_t, alpha, psi,
                                       ticket, done, dep, step_out, out);
}

// Round 2
// 565.655 us; speedup vs baseline: 1.2348x; 1.2348x over previous
//
#include <hip/hip_runtime.h>
#include <stdint.h>

#define NND 100000
#define HD  128
#define BB  512
#define DD  32
#define NNEG 5
#define CAP 12
#define ZROW 132            // zbuf row stride (pad +4 floats: breaks 8-way LDS conflicts)
#define SENT 0xAAAAAAAAu    // poison sentinel; sigmoid outputs are positive -> never equal

// ---------------- workspace layout (bytes) ----------------
#define OFF_WCNT     0                       // int[NND]
#define OFF_WSTEPS   400000                  // int[NND*CAP] packed s*64+slot
#define OFF_DEP      5200000                 // int[BB*38]
#define OFF_STEPOUT  5277824                 // float[BB*33*HD]
// total 13,928,576 bytes

__global__ void build_writers(const int* __restrict__ u,
                              const int* __restrict__ nb,
                              int* __restrict__ wcnt,
                              int* __restrict__ wsteps) {
    int id = blockIdx.x * blockDim.x + threadIdx.x;
    if (id >= BB * 33) return;
    int s = id / 33, slot = id % 33;
    int row = (slot == 0) ? u[s] : nb[s * DD + slot - 1];
    int pos = atomicAdd(&wcnt[row], 1);
    if (pos < CAP) wsteps[row * CAP + pos] = s * 64 + slot;
}

__global__ void build_deps(const int* __restrict__ u,
                           const int* __restrict__ nb,
                           const int* __restrict__ neg,
                           const int* __restrict__ wcnt,
                           const int* __restrict__ wsteps,
                           int* __restrict__ dep) {
    int id = blockIdx.x * blockDim.x + threadIdx.x;
    if (id >= BB * 38) return;
    int t = id / 38, i = id % 38;
    int row = (i == 0) ? u[t] : (i < 33) ? nb[t * DD + i - 1]
                                         : neg[t * NNEG + i - 33];
    int lim = t * 64;
    int best = -1;
    int n = wcnt[row]; if (n > CAP) n = CAP;
    for (int p = 0; p < n; p++) {
        int e = wsteps[row * CAP + p];
        if (e < lim && e > best) best = e;   // max (step,slot) < t == numpy last-write-wins
    }
    dep[id] = best;
}

__device__ __forceinline__ uint32_t mall_load(const uint32_t* p) {
    return __hip_atomic_load(p, __ATOMIC_RELAXED, __HIP_MEMORY_SCOPE_AGENT);
}
__device__ __forceinline__ void mall_store(float* p, float v) {
    __hip_atomic_store((uint32_t*)p, __float_as_uint(v),
                       __ATOMIC_RELAXED, __HIP_MEMORY_SCOPE_AGENT);
}

__global__ __launch_bounds__(256, 2)
void dyrep_main(const float* __restrict__ time_bar,
                const float* __restrict__ time_cur,
                const float* __restrict__ time_delta,
                const int* __restrict__ u,
                const int* __restrict__ nb,
                const int* __restrict__ neg,
                const float* __restrict__ z0,
                const float* __restrict__ W_omega, const float* __restrict__ b_omega,
                const float* __restrict__ W_h,     const float* __restrict__ b_h,
                const float* __restrict__ W_e2n,   const float* __restrict__ b_e2n,
                const float* __restrict__ W_rec_e, const float* __restrict__ b_rec_e,
                const float* __restrict__ W_rec_n, const float* __restrict__ b_rec_n,
                const float* __restrict__ W_time,  const float* __restrict__ b_time,
                const float* __restrict__ w_t_p,   const float* __restrict__ alpha_p,
                const float* __restrict__ psi_p,
                const int* __restrict__ dep,
                float* __restrict__ step_out,
                float* __restrict__ out) {
    __shared__ __align__(16) float zbuf[38][ZROW];   // 0=u, 1..32=nb, 33..37=neg
    __shared__ float sv[3][HD];                      // z_u@W_e2n, z_u@W_rec_e, m@W_h
    __shared__ float mvec[HD];
    __shared__ float td_arr[33];
    __shared__ const float* srcp[38];
    __shared__ int src_is_so[38];

    const int tid = threadIdx.x;
    const int t = blockIdx.x;

    // ---- resolve sources (no flags, no fences) ----
    if (tid < 38) {
        int i = tid;
        int d = dep[t * 38 + i];
        if (d >= 0) {
            srcp[i] = step_out + (size_t)(d >> 6) * 33 * HD + (size_t)(d & 63) * HD;
            src_is_so[i] = 1;
        } else {
            int row = (i == 0) ? u[t] : (i < 33) ? nb[t * DD + i - 1]
                                                 : neg[t * NNEG + i - 33];
            srcp[i] = z0 + (size_t)row * HD;
            src_is_so[i] = 0;
        }
    }
    __syncthreads();

    // ---- stage 38 rows into LDS; waiting == polling the data sentinel ----
    for (int idx = tid; idx < 38 * 32; idx += 256) {
        int slot = idx >> 5;
        int c4 = idx & 31;
        const float* sp = srcp[slot] + c4 * 4;
        float4 v;
        if (src_is_so[slot]) {
            const uint32_t* ip = (const uint32_t*)sp;
            uint32_t x0, x1, x2, x3;
            while (true) {
                x0 = mall_load(ip + 0);
                x1 = mall_load(ip + 1);
                x2 = mall_load(ip + 2);
                x3 = mall_load(ip + 3);
                if (x0 != SENT && x1 != SENT && x2 != SENT && x3 != SENT) break;
                __builtin_amdgcn_s_sleep(2);
            }
            v = make_float4(__uint_as_float(x0), __uint_as_float(x1),
                            __uint_as_float(x2), __uint_as_float(x3));
        } else {
            v = *(const float4*)sp;
        }
        *(float4*)&zbuf[slot][c4 * 4] = v;
    }
    const float tc = time_cur[t];
    __syncthreads();

    // ---- mean of neighbor rows + positional td ----
    if (tid < HD) {
        float s = 0.f;
        #pragma unroll
        for (int j = 1; j <= 32; j++) s += zbuf[j][tid];
        mvec[tid] = s * (1.0f / 32.0f);
    } else if (tid < HD + 33) {
        int j = tid - HD;
        td_arr[j] = tc - time_bar[(size_t)t * NND + j];
    }
    __syncthreads();

    // ---- single-row matvecs ----
    if (tid < HD) {
        float a1 = 0.f, a2 = 0.f;
        #pragma unroll 8
        for (int k = 0; k < HD; k++) {
            float a = zbuf[0][k];
            a1 = fmaf(a, W_e2n[k * HD + tid], a1);
            a2 = fmaf(a, W_rec_e[k * HD + tid], a2);
        }
        sv[0][tid] = a1; sv[1][tid] = a2;
    } else {
        int o = tid - HD;
        float a3 = 0.f;
        #pragma unroll 8
        for (int k = 0; k < HD; k++) a3 = fmaf(mvec[k], W_h[k * HD + o], a3);
        sv[2][o] = a3;
    }

    // ---- 32x128 @ 128x128 GEMM, 4x4 register tiles ----
    const int cg = tid & 31, rg = tid >> 5;
    const int c0 = cg * 4, r0 = rg * 4;
    float acc[4][4];
    #pragma unroll
    for (int r = 0; r < 4; r++)
        #pragma unroll
        for (int c = 0; c < 4; c++) acc[r][c] = 0.f;

    for (int kb = 0; kb < HD; kb += 4) {
        float av[4][4], wv[4][4];
        #pragma unroll
        for (int r = 0; r < 4; r++) {
            float4 aa = *(const float4*)&zbuf[1 + r0 + r][kb];
            av[r][0] = aa.x; av[r][1] = aa.y; av[r][2] = aa.z; av[r][3] = aa.w;
        }
        #pragma unroll
        for (int kk = 0; kk < 4; kk++) {
            float4 ww = *(const float4*)&W_rec_n[(size_t)(kb + kk) * HD + c0];
            wv[kk][0] = ww.x; wv[kk][1] = ww.y; wv[kk][2] = ww.z; wv[kk][3] = ww.w;
        }
        #pragma unroll
        for (int r = 0; r < 4; r++)
            #pragma unroll
            for (int c = 0; c < 4; c++) {
                float s = acc[r][c];
                s = fmaf(av[r][0], wv[0][c], s);
                s = fmaf(av[r][1], wv[1][c], s);
                s = fmaf(av[r][2], wv[2][c], s);
                s = fmaf(av[r][3], wv[3][c], s);
                acc[r][c] = s;
            }
    }
    __syncthreads();   // sv[] produced above must be visible to epilogue

    // ---- epilogue: h_nb (write-through agent stores: data IS the flag) ----
    float* my_out = step_out + (size_t)t * 33 * HD;
    #pragma unroll
    for (int r = 0; r < 4; r++) {
        int jj = r0 + r;
        float tdj = td_arr[1 + jj];
        #pragma unroll
        for (int c = 0; c < 4; c++) {
            int oo = c0 + c;
            float pre = acc[r][c] + sv[0][oo] + b_e2n[oo] + b_rec_n[oo]
                        + tdj * W_time[oo] + b_time[oo];
            mall_store(&my_out[(size_t)(1 + jj) * HD + oo],
                       1.f / (1.f + __expf(-pre)));
        }
    }
    // ---- h_u ----
    if (tid < HD) {
        float pre = sv[2][tid] + b_h[tid] + sv[1][tid] + b_rec_e[tid]
                    + td_arr[0] * W_time[tid] + b_time[tid];
        mall_store(&my_out[tid], 1.f / (1.f + __expf(-pre)));
    }

    // ---- Hawkes intensities on pre-update embeddings (wave 0, off critical path) ----
    if (tid < 64) {
        int lane = tid;
        float wt = *w_t_p, al = *alpha_p, ps = *psi_p, bom = *b_omega;
        float wo0 = W_omega[lane], wo1 = W_omega[lane + 64];
        for (int d = 0; d < 6; d++) {
            int slot = (d == 0) ? 0 : 32 + d;   // 0 or 33..37
            float v = zbuf[slot][lane] * wo0 + zbuf[slot][lane + 64] * wo1;
            #pragma unroll
            for (int off = 32; off; off >>= 1) v += __shfl_down(v, off);
            if (lane == 0) {
                float tdv;
                if (d == 0) tdv = tc - time_delta[t * 2 + 0];
                else {
                    int nn = neg[t * NNEG + (d - 1)];
                    tdv = tc - time_bar[(size_t)t * NND + nn];
                }
                float g = v + bom + al * __expf(-wt * tdv);
                float x = g / ps;
                float spv = fmaxf(x, 0.f) + log1pf(__expf(-fabsf(x)));
                float lam = ps * spv;
                if (d == 0) out[t] = lam;
                else out[BB + t * NNEG + (d - 1)] = lam * (1.0f / NNEG);
            }
        }
    }
    // no publish barrier, no fence: block just ends
}

extern "C" void kernel_launch(void* const* d_in, const int* in_sizes, int n_in,
                              void* d_out, int out_size, void* d_ws, size_t ws_size,
                              hipStream_t stream) {
    const float* time_bar  = (const float*)d_in[0];
    const float* time_cur  = (const float*)d_in[1];
    const float* time_delta= (const float*)d_in[2];
    const int*   u         = (const int*)d_in[3];
    const int*   nb        = (const int*)d_in[4];
    const int*   neg       = (const int*)d_in[5];
    const float* z0        = (const float*)d_in[6];
    const float* W_omega   = (const float*)d_in[7];
    const float* b_omega   = (const float*)d_in[8];
    const float* W_h       = (const float*)d_in[9];
    const float* b_h       = (const float*)d_in[10];
    const float* W_e2n     = (const float*)d_in[11];
    const float* b_e2n     = (const float*)d_in[12];
    const float* W_rec_e   = (const float*)d_in[13];
    const float* b_rec_e   = (const float*)d_in[14];
    const float* W_rec_n   = (const float*)d_in[15];
    const float* b_rec_n   = (const float*)d_in[16];
    const float* W_time    = (const float*)d_in[17];
    const float* b_time    = (const float*)d_in[18];
    const float* w_t       = (const float*)d_in[19];
    const float* alpha     = (const float*)d_in[20];
    const float* psi       = (const float*)d_in[21];

    char* ws = (char*)d_ws;
    int*   wcnt     = (int*)(ws + OFF_WCNT);
    int*   wsteps   = (int*)(ws + OFF_WSTEPS);
    int*   dep      = (int*)(ws + OFF_DEP);
    float* step_out = (float*)(ws + OFF_STEPOUT);
    float* out      = (float*)d_out;

    hipMemsetAsync(ws + OFF_WCNT, 0, NND * 4, stream);
    hipMemsetAsync(ws + OFF_STEPOUT, 0xAA, (size_t)BB * 33 * HD * 4, stream);
    build_writers<<<(BB * 33 + 255) / 256, 256, 0, stream>>>(u, nb, wcnt, wsteps);
    build_deps<<<(BB * 38 + 255) / 256, 256, 0, stream>>>(u, nb, neg, wcnt, wsteps, dep);
    dyrep_main<<<BB, 256, 0, stream>>>(time_bar, time_cur, time_delta, u, nb, neg, z0,
                                       W_omega, b_omega, W_h, b_h, W_e2n, b_e2n,
                                       W_rec_e, b_rec_e, W_rec_n, b_rec_n,
                                       W_time, b_time, w_t, alpha, psi,
                                       dep, step_out, out);
}

// Round 3
// 478.008 us; speedup vs baseline: 1.4613x; 1.1834x over previous
//
#include <hip/hip_runtime.h>
#include <stdint.h>

#define NND 100000
#define HD  128
#define BB  512
#define DD  32
#define NNEG 5
#define CAP 12
#define ZROW 132            // zbuf row stride in floats (528B, 16B-aligned, breaks conflicts)
#define SENT 0xAAAAAAAAu    // poison sentinel; sigmoid outputs are positive -> never equal

// ---------------- workspace layout (bytes) ----------------
#define OFF_WCNT     0                       // int[NND]
#define OFF_WSTEPS   400000                  // int[NND*CAP] packed s*64+slot
#define OFF_DEP      5200000                 // int[BB*38]
#define OFF_STEPOUT  5277824                 // float[BB*33*HD]

__global__ void build_writers(const int* __restrict__ u,
                              const int* __restrict__ nb,
                              int* __restrict__ wcnt,
                              int* __restrict__ wsteps) {
    int id = blockIdx.x * blockDim.x + threadIdx.x;
    if (id >= BB * 33) return;
    int s = id / 33, slot = id % 33;
    int row = (slot == 0) ? u[s] : nb[s * DD + slot - 1];
    int pos = atomicAdd(&wcnt[row], 1);
    if (pos < CAP) wsteps[row * CAP + pos] = s * 64 + slot;
}

__global__ void build_deps(const int* __restrict__ u,
                           const int* __restrict__ nb,
                           const int* __restrict__ neg,
                           const int* __restrict__ wcnt,
                           const int* __restrict__ wsteps,
                           int* __restrict__ dep) {
    int id = blockIdx.x * blockDim.x + threadIdx.x;
    if (id >= BB * 38) return;
    int t = id / 38, i = id % 38;
    int row = (i == 0) ? u[t] : (i < 33) ? nb[t * DD + i - 1]
                                         : neg[t * NNEG + i - 33];
    int lim = t * 64;
    int best = -1;
    int n = wcnt[row]; if (n > CAP) n = CAP;
    for (int p = 0; p < n; p++) {
        int e = wsteps[row * CAP + p];
        if (e < lim && e > best) best = e;   // max (step,slot) < t == numpy last-write-wins
    }
    dep[id] = best;
}

__device__ __forceinline__ uint32_t mall_load(const uint32_t* p) {
    return __hip_atomic_load(p, __ATOMIC_RELAXED, __HIP_MEMORY_SCOPE_AGENT);
}
__device__ __forceinline__ void mall_store(float* p, float v) {
    __hip_atomic_store((uint32_t*)p, __float_as_uint(v),
                       __ATOMIC_RELAXED, __HIP_MEMORY_SCOPE_AGENT);
}

// length-128 dot of LDS vector (broadcast) with global weight column, 16-deep
// double-buffered prefetch so L2 latency hides behind FMA issue.
__device__ __forceinline__ float dot128_pf(const float* __restrict__ W, int col,
                                           const float* __restrict__ zrow) {
    float acc = 0.f;
    float wb0[16], wb1[16];
    #pragma unroll
    for (int j = 0; j < 16; j++) wb0[j] = W[j * HD + col];
    #pragma unroll
    for (int kb = 0; kb < 128; kb += 32) {
        #pragma unroll
        for (int j = 0; j < 16; j++) wb1[j] = W[(kb + 16 + j) * HD + col];
        #pragma unroll
        for (int j = 0; j < 16; j++) acc = fmaf(zrow[kb + j], wb0[j], acc);
        if (kb + 32 < 128) {
            #pragma unroll
            for (int j = 0; j < 16; j++) wb0[j] = W[(kb + 32 + j) * HD + col];
        }
        #pragma unroll
        for (int j = 0; j < 16; j++) acc = fmaf(zrow[kb + 16 + j], wb1[j], acc);
    }
    return acc;
}

__device__ __forceinline__ void fma4x4(float acc[4][4], const float4 av[4],
                                       const float4 wv[4]) {
    #pragma unroll
    for (int r = 0; r < 4; r++) {
        const float ar[4] = {av[r].x, av[r].y, av[r].z, av[r].w};
        #pragma unroll
        for (int kk = 0; kk < 4; kk++) {
            const float* wk = (const float*)&wv[kk];
            #pragma unroll
            for (int c = 0; c < 4; c++)
                acc[r][c] = fmaf(ar[kk], wk[c], acc[r][c]);
        }
    }
}

__global__ __launch_bounds__(256, 2)
void dyrep_main(const float* __restrict__ time_bar,
                const float* __restrict__ time_cur,
                const float* __restrict__ time_delta,
                const int* __restrict__ u,
                const int* __restrict__ nb,
                const int* __restrict__ neg,
                const float* __restrict__ z0,
                const float* __restrict__ W_omega, const float* __restrict__ b_omega,
                const float* __restrict__ W_h,     const float* __restrict__ b_h,
                const float* __restrict__ W_e2n,   const float* __restrict__ b_e2n,
                const float* __restrict__ W_rec_e, const float* __restrict__ b_rec_e,
                const float* __restrict__ W_rec_n, const float* __restrict__ b_rec_n,
                const float* __restrict__ W_time,  const float* __restrict__ b_time,
                const float* __restrict__ w_t_p,   const float* __restrict__ alpha_p,
                const float* __restrict__ psi_p,
                const int* __restrict__ dep,
                float* __restrict__ step_out,
                float* __restrict__ out) {
    __shared__ __align__(16) float zbuf[38][ZROW];   // 0=u, 1..32=nb, 33..37=neg
    __shared__ float mvec[HD];
    __shared__ float sv_e2n[HD];     // z_u @ W_e2n
    __shared__ float sv_u[HD];       // z_u @ W_rec_e + mvec @ W_h
    __shared__ float td_arr[33];
    __shared__ float tdv_sh[6];
    __shared__ float cb_nb[HD], cb_u[HD], wt_sh[HD];
    __shared__ const float* srcp[38];
    __shared__ int src_is_so[38];

    const int tid = threadIdx.x;
    const int t = blockIdx.x;
    float* zflat = &zbuf[0][0];

    // ---- pre-phase: everything that does NOT depend on predecessors ----
    if (tid < 38) {
        int i = tid;
        int d = dep[t * 38 + i];
        if (d >= 0) {
            srcp[i] = step_out + (size_t)(d >> 6) * 33 * HD + (size_t)(d & 63) * HD;
            src_is_so[i] = 1;
        } else {
            int row = (i == 0) ? u[t] : (i < 33) ? nb[t * DD + i - 1]
                                                 : neg[t * NNEG + i - 33];
            srcp[i] = z0 + (size_t)row * HD;
            src_is_so[i] = 0;
        }
    } else if (tid < 71) {
        int j = tid - 38;
        td_arr[j] = time_cur[t] - time_bar[(size_t)t * NND + j];
    } else if (tid < 77) {
        int d = tid - 71;
        float tc = time_cur[t];
        if (d == 0) tdv_sh[0] = tc - time_delta[t * 2 + 0];
        else {
            int nn = neg[t * NNEG + (d - 1)];
            tdv_sh[d] = tc - time_bar[(size_t)t * NND + nn];
        }
    }
    if (tid < HD) {
        cb_nb[tid] = b_e2n[tid] + b_rec_n[tid] + b_time[tid];
    } else {
        int c = tid - HD;
        cb_u[c] = b_h[c] + b_rec_e[c] + b_time[c];
        wt_sh[c] = W_time[c];
    }
    float wo0 = 0.f, wo1 = 0.f, wt = 0.f, al = 0.f, ps = 0.f, bom = 0.f;
    if (tid < 64) {
        wo0 = W_omega[tid]; wo1 = W_omega[tid + 64];
        wt = *w_t_p; al = *alpha_p; ps = *psi_p; bom = *b_omega;
    }
    __syncthreads();

    // ---- staging: z0 rows immediately; step_out rows via round-robin polling ----
    int nmine = 0;
    const uint32_t* pp[5];
    int lofs[5];
    for (int idx = tid; idx < 38 * 32; idx += 256) {
        int slot = idx >> 5, c4 = idx & 31;
        const float* sp = srcp[slot] + c4 * 4;
        int lo = slot * ZROW + c4 * 4;
        if (src_is_so[slot]) {
            pp[nmine] = (const uint32_t*)sp;
            lofs[nmine] = lo;
            nmine++;
        } else {
            *(float4*)&zflat[lo] = *(const float4*)sp;
        }
    }
    unsigned pend = (nmine > 0) ? ((1u << nmine) - 1u) : 0u;
    while (pend) {
        unsigned rem = pend;
        while (rem) {
            int i = __ffs(rem) - 1;
            rem &= rem - 1u;
            const uint32_t* q = pp[i];
            uint32_t x0 = mall_load(q + 0), x1 = mall_load(q + 1);
            uint32_t x2 = mall_load(q + 2), x3 = mall_load(q + 3);
            if (x0 != SENT && x1 != SENT && x2 != SENT && x3 != SENT) {
                *(float4*)&zflat[lofs[i]] =
                    make_float4(__uint_as_float(x0), __uint_as_float(x1),
                                __uint_as_float(x2), __uint_as_float(x3));
                pend &= ~(1u << i);
            }
        }
        if (pend) __builtin_amdgcn_s_sleep(1);
    }
    __syncthreads();

    // ---- phase 1: A = mean of neighbors; B = z_u @ W_rec_e ----
    if (tid < HD) {
        float s = 0.f;
        #pragma unroll
        for (int j = 1; j <= 32; j++) s += zbuf[j][tid];
        mvec[tid] = s * (1.0f / 32.0f);
    } else {
        int col = tid - HD;
        sv_u[col] = dot128_pf(W_rec_e, col, &zbuf[0][0]);
    }
    __syncthreads();   // mvec ready for B's second dot

    // ---- phase 2: A = z_u @ W_e2n; B = += mvec @ W_h ----
    if (tid < HD) {
        sv_e2n[tid] = dot128_pf(W_e2n, tid, &zbuf[0][0]);
    } else {
        int col = tid - HD;
        sv_u[col] += dot128_pf(W_h, col, mvec);
    }
    // no barrier: GEMM below is per-thread independent of sv_*

    // ---- 32x128 @ 128x128 GEMM, 4x4 tiles, ping-pong prefetch ----
    const int cg = tid & 31, rg = tid >> 5;
    const int c0 = cg * 4, r0 = rg * 4;
    float acc[4][4];
    #pragma unroll
    for (int r = 0; r < 4; r++)
        #pragma unroll
        for (int c = 0; c < 4; c++) acc[r][c] = 0.f;

    float4 avA[4], wvA[4], avB[4], wvB[4];
    #pragma unroll
    for (int r = 0; r < 4; r++) avA[r] = *(const float4*)&zbuf[1 + r0 + r][0];
    #pragma unroll
    for (int kk = 0; kk < 4; kk++) wvA[kk] = *(const float4*)&W_rec_n[(size_t)kk * HD + c0];

    for (int kb = 0; kb < HD; kb += 8) {
        #pragma unroll
        for (int r = 0; r < 4; r++) avB[r] = *(const float4*)&zbuf[1 + r0 + r][kb + 4];
        #pragma unroll
        for (int kk = 0; kk < 4; kk++)
            wvB[kk] = *(const float4*)&W_rec_n[(size_t)(kb + 4 + kk) * HD + c0];
        fma4x4(acc, avA, wvA);
        if (kb + 8 < HD) {
            #pragma unroll
            for (int r = 0; r < 4; r++) avA[r] = *(const float4*)&zbuf[1 + r0 + r][kb + 8];
            #pragma unroll
            for (int kk = 0; kk < 4; kk++)
                wvA[kk] = *(const float4*)&W_rec_n[(size_t)(kb + 8 + kk) * HD + c0];
        }
        fma4x4(acc, avB, wvB);
    }
    __syncthreads();   // sv_e2n / sv_u visible for epilogue

    // ---- epilogue: h_nb rows (write-through stores: data IS the flag) ----
    float* my_out = step_out + (size_t)t * 33 * HD;
    #pragma unroll
    for (int r = 0; r < 4; r++) {
        int jj = r0 + r;
        float tdj = td_arr[1 + jj];
        #pragma unroll
        for (int c = 0; c < 4; c++) {
            int oo = c0 + c;
            float pre = acc[r][c] + sv_e2n[oo] + tdj * wt_sh[oo] + cb_nb[oo];
            mall_store(&my_out[(size_t)(1 + jj) * HD + oo],
                       1.f / (1.f + __expf(-pre)));
        }
    }
    // ---- h_u ----
    if (tid < HD) {
        float pre = sv_u[tid] + td_arr[0] * wt_sh[tid] + cb_u[tid];
        mall_store(&my_out[tid], 1.f / (1.f + __expf(-pre)));
    }

    // ---- Hawkes intensities (wave 0, off the inter-block critical path) ----
    if (tid < 64) {
        #pragma unroll
        for (int d = 0; d < 6; d++) {
            int slot = (d == 0) ? 0 : 32 + d;   // 0 or 33..37
            float v = zbuf[slot][tid] * wo0 + zbuf[slot][tid + 64] * wo1;
            #pragma unroll
            for (int off = 32; off; off >>= 1) v += __shfl_down(v, off);
            if (tid == 0) {
                float g = v + bom + al * __expf(-wt * tdv_sh[d]);
                float x = g / ps;
                float spv = fmaxf(x, 0.f) + log1pf(__expf(-fabsf(x)));
                float lam = ps * spv;
                if (d == 0) out[t] = lam;
                else out[BB + t * NNEG + (d - 1)] = lam * (1.0f / NNEG);
            }
        }
    }
}

extern "C" void kernel_launch(void* const* d_in, const int* in_sizes, int n_in,
                              void* d_out, int out_size, void* d_ws, size_t ws_size,
                              hipStream_t stream) {
    const float* time_bar  = (const float*)d_in[0];
    const float* time_cur  = (const float*)d_in[1];
    const float* time_delta= (const float*)d_in[2];
    const int*   u         = (const int*)d_in[3];
    const int*   nb        = (const int*)d_in[4];
    const int*   neg       = (const int*)d_in[5];
    const float* z0        = (const float*)d_in[6];
    const float* W_omega   = (const float*)d_in[7];
    const float* b_omega   = (const float*)d_in[8];
    const float* W_h       = (const float*)d_in[9];
    const float* b_h       = (const float*)d_in[10];
    const float* W_e2n     = (const float*)d_in[11];
    const float* b_e2n     = (const float*)d_in[12];
    const float* W_rec_e   = (const float*)d_in[13];
    const float* b_rec_e   = (const float*)d_in[14];
    const float* W_rec_n   = (const float*)d_in[15];
    const float* b_rec_n   = (const float*)d_in[16];
    const float* W_time    = (const float*)d_in[17];
    const float* b_time    = (const float*)d_in[18];
    const float* w_t       = (const float*)d_in[19];
    const float* alpha     = (const float*)d_in[20];
    const float* psi       = (const float*)d_in[21];

    char* ws = (char*)d_ws;
    int*   wcnt     = (int*)(ws + OFF_WCNT);
    int*   wsteps   = (int*)(ws + OFF_WSTEPS);
    int*   dep      = (int*)(ws + OFF_DEP);
    float* step_out = (float*)(ws + OFF_STEPOUT);
    float* out      = (float*)d_out;

    hipMemsetAsync(ws + OFF_WCNT, 0, NND * 4, stream);
    hipMemsetAsync(ws + OFF_STEPOUT, 0xAA, (size_t)BB * 33 * HD * 4, stream);
    build_writers<<<(BB * 33 + 255) / 256, 256, 0, stream>>>(u, nb, wcnt, wsteps);
    build_deps<<<(BB * 38 + 255) / 256, 256, 0, stream>>>(u, nb, neg, wcnt, wsteps, dep);
    dyrep_main<<<BB, 256, 0, stream>>>(time_bar, time_cur, time_delta, u, nb, neg, z0,
                                       W_omega, b_omega, W_h, b_h, W_e2n, b_e2n,
                                       W_rec_e, b_rec_e, W_rec_n, b_rec_n,
                                       W_time, b_time, w_t, alpha, psi,
                                       dep, step_out, out);
}

// Round 4
// 387.932 us; speedup vs baseline: 1.8006x; 1.2322x over previous
//
#include <hip/hip_runtime.h>
#include <stdint.h>

#define NND 100000
#define HD  128
#define BB  512
#define DD  32
#define NNEG 5
#define CAP 12
#define ZROW 132
#define SENT 0xAAAAAAAAu

// ---------------- workspace layout (bytes) ----------------
#define OFF_WCNT     0                       // int[NND]
#define OFF_WSTEPS   400000                  // int[NND*CAP] packed s*64+slot
#define OFF_DEP      5200000                 // int[BB*38]
#define OFF_STEPOUT  5277824                 // float[BB*33*HD]

__global__ void build_writers(const int* __restrict__ u,
                              const int* __restrict__ nb,
                              int* __restrict__ wcnt,
                              int* __restrict__ wsteps) {
    int id = blockIdx.x * blockDim.x + threadIdx.x;
    if (id >= BB * 33) return;
    int s = id / 33, slot = id % 33;
    int row = (slot == 0) ? u[s] : nb[s * DD + slot - 1];
    int pos = atomicAdd(&wcnt[row], 1);
    if (pos < CAP) wsteps[row * CAP + pos] = s * 64 + slot;
}

__global__ void build_deps(const int* __restrict__ u,
                           const int* __restrict__ nb,
                           const int* __restrict__ neg,
                           const int* __restrict__ wcnt,
                           const int* __restrict__ wsteps,
                           int* __restrict__ dep) {
    int id = blockIdx.x * blockDim.x + threadIdx.x;
    if (id >= BB * 38) return;
    int t = id / 38, i = id % 38;
    int row = (i == 0) ? u[t] : (i < 33) ? nb[t * DD + i - 1]
                                         : neg[t * NNEG + i - 33];
    int lim = t * 64;
    int best = -1;
    int n = wcnt[row]; if (n > CAP) n = CAP;
    for (int p = 0; p < n; p++) {
        int e = wsteps[row * CAP + p];
        if (e < lim && e > best) best = e;   // max (step,slot) < t == numpy last-write-wins
    }
    dep[id] = best;
}

__device__ __forceinline__ uint32_t mall_load(const uint32_t* p) {
    return __hip_atomic_load(p, __ATOMIC_RELAXED, __HIP_MEMORY_SCOPE_AGENT);
}
__device__ __forceinline__ void mall_store2(float* p, float v0, float v1) {
    uint64_t pk = ((uint64_t)__float_as_uint(v1) << 32) | (uint64_t)__float_as_uint(v0);
    __hip_atomic_store((unsigned long long*)p, (unsigned long long)pk,
                       __ATOMIC_RELAXED, __HIP_MEMORY_SCOPE_AGENT);
}
__device__ __forceinline__ void flag_set(int* f) {
    __hip_atomic_store(f, 1, __ATOMIC_RELEASE, __HIP_MEMORY_SCOPE_WORKGROUP);
}
__device__ __forceinline__ void flag_wait(int* f) {
    while (__hip_atomic_load(f, __ATOMIC_ACQUIRE, __HIP_MEMORY_SCOPE_WORKGROUP) == 0)
        __builtin_amdgcn_s_sleep(1);
}

__global__ __launch_bounds__(512, 4)
void dyrep_main(const float* __restrict__ time_bar,
                const float* __restrict__ time_cur,
                const float* __restrict__ time_delta,
                const int* __restrict__ u,
                const int* __restrict__ nb,
                const int* __restrict__ neg,
                const float* __restrict__ z0,
                const float* __restrict__ W_omega, const float* __restrict__ b_omega,
                const float* __restrict__ W_h,     const float* __restrict__ b_h,
                const float* __restrict__ W_e2n,   const float* __restrict__ b_e2n,
                const float* __restrict__ W_rec_e, const float* __restrict__ b_rec_e,
                const float* __restrict__ W_rec_n, const float* __restrict__ b_rec_n,
                const float* __restrict__ W_time,  const float* __restrict__ b_time,
                const float* __restrict__ w_t_p,   const float* __restrict__ alpha_p,
                const float* __restrict__ psi_p,
                const int* __restrict__ dep,
                float* __restrict__ step_out,
                float* __restrict__ out) {
    __shared__ float zu[HD];
    __shared__ __align__(16) float znb[DD][ZROW];
    __shared__ float psum[8][HD];
    __shared__ float mbuf[HD];
    __shared__ int flag_zu;
    __shared__ int flag_ps[8];

    const int tid  = threadIdx.x;
    const int lane = tid & 63;
    const int wid  = tid >> 6;
    const int t    = blockIdx.x;
    const int c0   = lane * 2;          // this lane's two output columns

    if (tid == 0) flag_zu = 0;
    if (tid < 8)  flag_ps[tid] = 0;
    __syncthreads();

    // ---------- per-wave dep-independent preloads ----------
    const float tc  = time_cur[t];
    const float cb0 = b_e2n[c0] + b_rec_n[c0] + b_time[c0];
    const float cb1 = b_e2n[c0+1] + b_rec_n[c0+1] + b_time[c0+1];
    const float wt0 = W_time[c0], wt1 = W_time[c0+1];
    float td_r[4];
    #pragma unroll
    for (int r = 0; r < 4; r++)
        td_r[r] = tc - time_bar[(size_t)t * NND + (1 + 4*wid + r)];

    // wave-0 extras
    float cbu0=0.f, cbu1=0.f, td0=0.f, wo0=0.f, wo1=0.f, wt=0.f, al=0.f, ps=0.f, bom=0.f;
    float tdv[6];
    int   negdep[5]; const float* negsrc[5];
    if (wid == 0) {
        cbu0 = b_h[c0] + b_rec_e[c0] + b_time[c0];
        cbu1 = b_h[c0+1] + b_rec_e[c0+1] + b_time[c0+1];
        td0  = tc - time_bar[(size_t)t * NND + 0];
        wo0  = W_omega[c0]; wo1 = W_omega[c0+1];
        wt = *w_t_p; al = *alpha_p; ps = *psi_p; bom = *b_omega;
        tdv[0] = tc - time_delta[t * 2 + 0];
        #pragma unroll
        for (int d = 0; d < 5; d++) {
            int nn = neg[t * NNEG + d];
            tdv[1 + d] = tc - time_bar[(size_t)t * NND + nn];
            int dv = negdep[d] = dep[t * 38 + 33 + d];
            negsrc[d] = (dv >= 0)
                ? step_out + (size_t)(dv >> 6) * 33 * HD + (size_t)(dv & 63) * HD
                : z0 + (size_t)nn * HD;
        }
    }

    // ---------- wave 0: stage z_u (gates every wave's epilogue) ----------
    if (wid == 0) {
        int d = dep[t * 38 + 0];
        const float* src = (d >= 0)
            ? step_out + (size_t)(d >> 6) * 33 * HD + (size_t)(d & 63) * HD
            : z0 + (size_t)u[t] * HD;
        if (lane < 32) {
            const float* sp = src + lane * 4;
            float4 v;
            if (d >= 0) {
                const uint32_t* ip = (const uint32_t*)sp;
                uint32_t x0, x1, x2, x3;
                while (true) {
                    x0 = mall_load(ip+0); x1 = mall_load(ip+1);
                    x2 = mall_load(ip+2); x3 = mall_load(ip+3);
                    if (x0 != SENT && x1 != SENT && x2 != SENT && x3 != SENT) break;
                    __builtin_amdgcn_s_sleep(1);
                }
                v = make_float4(__uint_as_float(x0), __uint_as_float(x1),
                                __uint_as_float(x2), __uint_as_float(x3));
            } else {
                v = *(const float4*)sp;
            }
            *(float4*)&zu[lane * 4] = v;
        }
        __threadfence_block();
        if (lane == 0) flag_set(&flag_zu);
    }

    // ---------- stage this wave's 4 neighbor rows (poll = wait) ----------
    {
        const uint32_t* pollp[2]; int lofs[2]; float4 direct[2];
        unsigned pend = 0;
        #pragma unroll
        for (int q = 0; q < 2; q++) {
            int idx = lane + q * 64;
            int rl = idx >> 5, c4 = idx & 31;
            int j = 4 * wid + rl;
            int d = dep[t * 38 + 1 + j];
            const float* sp = (d >= 0)
                ? step_out + (size_t)(d >> 6) * 33 * HD + (size_t)(d & 63) * HD
                : z0 + (size_t)nb[t * DD + j] * HD;
            sp += c4 * 4;
            lofs[q] = j * ZROW + c4 * 4;
            if (d >= 0) { pollp[q] = (const uint32_t*)sp; pend |= (1u << q); }
            else direct[q] = *(const float4*)sp;
        }
        float* zflat = &znb[0][0];
        #pragma unroll
        for (int q = 0; q < 2; q++)
            if (!((pend >> q) & 1)) *(float4*)&zflat[lofs[q]] = direct[q];
        while (__ballot(pend != 0) != 0ULL) {
            #pragma unroll
            for (int q = 0; q < 2; q++) {
                if ((pend >> q) & 1) {
                    const uint32_t* ip = pollp[q];
                    uint32_t x0 = mall_load(ip+0), x1 = mall_load(ip+1);
                    uint32_t x2 = mall_load(ip+2), x3 = mall_load(ip+3);
                    if (x0 != SENT && x1 != SENT && x2 != SENT && x3 != SENT) {
                        *(float4*)&zflat[lofs[q]] =
                            make_float4(__uint_as_float(x0), __uint_as_float(x1),
                                        __uint_as_float(x2), __uint_as_float(x3));
                        pend &= ~(1u << q);
                    }
                }
            }
            if (pend) __builtin_amdgcn_s_sleep(1);
        }
    }
    __threadfence_block();   // own-wave LDS writes visible before reads

    // ---------- psum (column sums of my 4 rows) + release ----------
    {
        float s0 = 0.f, s1 = 0.f;
        #pragma unroll
        for (int r = 0; r < 4; r++) {
            float2 zz = *(const float2*)&znb[4*wid + r][c0];
            s0 += zz.x; s1 += zz.y;
        }
        psum[wid][c0] = s0; psum[wid][c0+1] = s1;
        if (lane == 0) flag_set(&flag_ps[wid]);   // release waits lgkmcnt(0)
        else __builtin_amdgcn_s_sleep(0);
    }

    // ---------- 4x128 @ 128x128 GEMM (2 cols/lane), ping-pong prefetch ----------
    float2 acc[4];
    #pragma unroll
    for (int r = 0; r < 4; r++) { acc[r].x = 0.f; acc[r].y = 0.f; }
    {
        const float* zr[4];
        #pragma unroll
        for (int r = 0; r < 4; r++) zr[r] = &znb[4*wid + r][0];
        float4 zA[4], zB[4]; float2 wA[4], wB[4];
        #pragma unroll
        for (int r = 0; r < 4; r++) zA[r] = *(const float4*)&zr[r][0];
        #pragma unroll
        for (int kk = 0; kk < 4; kk++) wA[kk] = *(const float2*)&W_rec_n[(size_t)kk * HD + c0];
        for (int kb = 0; kb < HD; kb += 8) {
            #pragma unroll
            for (int r = 0; r < 4; r++) zB[r] = *(const float4*)&zr[r][kb + 4];
            #pragma unroll
            for (int kk = 0; kk < 4; kk++)
                wB[kk] = *(const float2*)&W_rec_n[(size_t)(kb + 4 + kk) * HD + c0];
            #pragma unroll
            for (int r = 0; r < 4; r++) {
                const float za[4] = {zA[r].x, zA[r].y, zA[r].z, zA[r].w};
                #pragma unroll
                for (int kk = 0; kk < 4; kk++) {
                    acc[r].x = fmaf(za[kk], wA[kk].x, acc[r].x);
                    acc[r].y = fmaf(za[kk], wA[kk].y, acc[r].y);
                }
            }
            if (kb + 8 < HD) {
                #pragma unroll
                for (int r = 0; r < 4; r++) zA[r] = *(const float4*)&zr[r][kb + 8];
                #pragma unroll
                for (int kk = 0; kk < 4; kk++)
                    wA[kk] = *(const float2*)&W_rec_n[(size_t)(kb + 8 + kk) * HD + c0];
            }
            #pragma unroll
            for (int r = 0; r < 4; r++) {
                const float zb[4] = {zB[r].x, zB[r].y, zB[r].z, zB[r].w};
                #pragma unroll
                for (int kk = 0; kk < 4; kk++) {
                    acc[r].x = fmaf(zb[kk], wB[kk].x, acc[r].x);
                    acc[r].y = fmaf(zb[kk], wB[kk].y, acc[r].y);
                }
            }
        }
    }

    // ---------- my 2-col slice of z_u @ W_e2n, then sigmoid + publish ----------
    flag_wait(&flag_zu);
    float e0 = 0.f, e1 = 0.f;
    {
        float4 zA = *(const float4*)&zu[0];
        float2 wA[4], wB[4]; float4 zB;
        #pragma unroll
        for (int kk = 0; kk < 4; kk++) wA[kk] = *(const float2*)&W_e2n[(size_t)kk * HD + c0];
        for (int kb = 0; kb < HD; kb += 8) {
            zB = *(const float4*)&zu[kb + 4];
            #pragma unroll
            for (int kk = 0; kk < 4; kk++)
                wB[kk] = *(const float2*)&W_e2n[(size_t)(kb + 4 + kk) * HD + c0];
            const float za[4] = {zA.x, zA.y, zA.z, zA.w};
            #pragma unroll
            for (int kk = 0; kk < 4; kk++) {
                e0 = fmaf(za[kk], wA[kk].x, e0);
                e1 = fmaf(za[kk], wA[kk].y, e1);
            }
            if (kb + 8 < HD) {
                zA = *(const float4*)&zu[kb + 8];
                #pragma unroll
                for (int kk = 0; kk < 4; kk++)
                    wA[kk] = *(const float2*)&W_e2n[(size_t)(kb + 8 + kk) * HD + c0];
            }
            const float zb[4] = {zB.x, zB.y, zB.z, zB.w};
            #pragma unroll
            for (int kk = 0; kk < 4; kk++) {
                e0 = fmaf(zb[kk], wB[kk].x, e0);
                e1 = fmaf(zb[kk], wB[kk].y, e1);
            }
        }
    }
    float* my_out = step_out + (size_t)t * 33 * HD;
    #pragma unroll
    for (int r = 0; r < 4; r++) {
        int j = 4 * wid + r;
        float p0 = acc[r].x + e0 + td_r[r] * wt0 + cb0;
        float p1 = acc[r].y + e1 + td_r[r] * wt1 + cb1;
        mall_store2(&my_out[(size_t)(1 + j) * HD + c0],
                    1.f / (1.f + __expf(-p0)), 1.f / (1.f + __expf(-p1)));
    }

    if (wid != 0) return;

    // ---------- wave 0: h_u = sigmoid(mean@W_h + z_u@W_rec_e + ...) ----------
    #pragma unroll
    for (int g = 0; g < 8; g++) flag_wait(&flag_ps[g]);
    {
        float m0 = 0.f, m1 = 0.f;
        #pragma unroll
        for (int g = 0; g < 8; g++) { m0 += psum[g][c0]; m1 += psum[g][c0+1]; }
        mbuf[c0] = m0 * (1.f/32.f); mbuf[c0+1] = m1 * (1.f/32.f);
    }
    __threadfence_block();
    {
        float a0 = 0.f, a1 = 0.f;
        for (int kb = 0; kb < HD; kb += 4) {
            float4 mv = *(const float4*)&mbuf[kb];
            float4 zv = *(const float4*)&zu[kb];
            const float mm[4] = {mv.x, mv.y, mv.z, mv.w};
            const float zz[4] = {zv.x, zv.y, zv.z, zv.w};
            #pragma unroll
            for (int kk = 0; kk < 4; kk++) {
                float2 wh = *(const float2*)&W_h[(size_t)(kb + kk) * HD + c0];
                float2 wr = *(const float2*)&W_rec_e[(size_t)(kb + kk) * HD + c0];
                a0 = fmaf(mm[kk], wh.x, fmaf(zz[kk], wr.x, a0));
                a1 = fmaf(mm[kk], wh.y, fmaf(zz[kk], wr.y, a1));
            }
        }
        float p0 = a0 + td0 * wt0 + cbu0;
        float p1 = a1 + td0 * wt1 + cbu1;
        mall_store2(&my_out[c0], 1.f / (1.f + __expf(-p0)), 1.f / (1.f + __expf(-p1)));
    }

    // ---------- wave 0: Hawkes lambdas (off the DAG critical path) ----------
    {
        // emb_u
        float v = zu[c0] * wo0 + zu[c0+1] * wo1;
        #pragma unroll
        for (int off = 32; off; off >>= 1) v += __shfl_down(v, off);
        if (lane == 0) {
            float g = v + bom + al * __expf(-wt * tdv[0]);
            float x = g / ps;
            out[t] = ps * (fmaxf(x, 0.f) + log1pf(__expf(-fabsf(x))));
        }
        // negatives
        for (int d = 0; d < 5; d++) {
            const float* sp = negsrc[d] + c0;
            float x0, x1;
            if (negdep[d] >= 0) {
                const uint32_t* ip = (const uint32_t*)sp;
                uint32_t a, b;
                while (true) {
                    a = mall_load(ip + 0); b = mall_load(ip + 1);
                    if (a != SENT && b != SENT) break;
                    __builtin_amdgcn_s_sleep(1);
                }
                x0 = __uint_as_float(a); x1 = __uint_as_float(b);
            } else {
                x0 = sp[0]; x1 = sp[1];
            }
            float v2 = x0 * wo0 + x1 * wo1;
            #pragma unroll
            for (int off = 32; off; off >>= 1) v2 += __shfl_down(v2, off);
            if (lane == 0) {
                float g = v2 + bom + al * __expf(-wt * tdv[1 + d]);
                float x = g / ps;
                out[BB + t * NNEG + d] =
                    ps * (fmaxf(x, 0.f) + log1pf(__expf(-fabsf(x)))) * (1.0f / NNEG);
            }
        }
    }
}

extern "C" void kernel_launch(void* const* d_in, const int* in_sizes, int n_in,
                              void* d_out, int out_size, void* d_ws, size_t ws_size,
                              hipStream_t stream) {
    const float* time_bar  = (const float*)d_in[0];
    const float* time_cur  = (const float*)d_in[1];
    const float* time_delta= (const float*)d_in[2];
    const int*   u         = (const int*)d_in[3];
    const int*   nb        = (const int*)d_in[4];
    const int*   neg       = (const int*)d_in[5];
    const float* z0        = (const float*)d_in[6];
    const float* W_omega   = (const float*)d_in[7];
    const float* b_omega   = (const float*)d_in[8];
    const float* W_h       = (const float*)d_in[9];
    const float* b_h       = (const float*)d_in[10];
    const float* W_e2n     = (const float*)d_in[11];
    const float* b_e2n     = (const float*)d_in[12];
    const float* W_rec_e   = (const float*)d_in[13];
    const float* b_rec_e   = (const float*)d_in[14];
    const float* W_rec_n   = (const float*)d_in[15];
    const float* b_rec_n   = (const float*)d_in[16];
    const float* W_time    = (const float*)d_in[17];
    const float* b_time    = (const float*)d_in[18];
    const float* w_t       = (const float*)d_in[19];
    const float* alpha     = (const float*)d_in[20];
    const float* psi       = (const float*)d_in[21];

    char* ws = (char*)d_ws;
    int*   wcnt     = (int*)(ws + OFF_WCNT);
    int*   wsteps   = (int*)(ws + OFF_WSTEPS);
    int*   dep      = (int*)(ws + OFF_DEP);
    float* step_out = (float*)(ws + OFF_STEPOUT);
    float* out      = (float*)d_out;

    hipMemsetAsync(ws + OFF_WCNT, 0, NND * 4, stream);
    hipMemsetAsync(ws + OFF_STEPOUT, 0xAA, (size_t)BB * 33 * HD * 4, stream);
    build_writers<<<(BB * 33 + 255) / 256, 256, 0, stream>>>(u, nb, wcnt, wsteps);
    build_deps<<<(BB * 38 + 255) / 256, 256, 0, stream>>>(u, nb, neg, wcnt, wsteps, dep);
    dyrep_main<<<BB, 512, 0, stream>>>(time_bar, time_cur, time_delta, u, nb, neg, z0,
                                       W_omega, b_omega, W_h, b_h, W_e2n, b_e2n,
                                       W_rec_e, b_rec_e, W_rec_n, b_rec_n,
                                       W_time, b_time, w_t, alpha, psi,
                                       dep, step_out, out);
}